// Round 4
// baseline (1401.621 us; speedup 1.0000x reference)
//
#include <hip/hip_runtime.h>
#include <cstddef>

constexpr int V_CNT = 65536;
constexpr int E_CNT = 1048576;
constexpr int H_DIM = 128;
constexpr int CI = 34;   // chem in
constexpr int GI = 48;   // geom in
constexpr int VB = 4;    // vertices per chem block
#define EPSF 1e-5f

typedef _Float16 f16;
typedef f16 f16x8 __attribute__((ext_vector_type(8)));
typedef float f32x4 __attribute__((ext_vector_type(4)));
#define MFMA16(a,b,c) __builtin_amdgcn_mfma_f32_16x16x32_f16(a,b,c,0,0,0)

__device__ __forceinline__ float sigmoidf_(float x){ return 1.0f/(1.0f+__expf(-x)); }
__device__ __forceinline__ float siluf_(float x){ return x/(1.0f+__expf(-x)); }
__device__ __forceinline__ float softplusf_(float x){
  return fmaxf(x,0.0f) + __logf(1.0f + __expf(-fabsf(x)));
}

// ---------------- prep: fold BN scale into all weights, convert to f16 col-major [col][k]
__global__ __launch_bounds__(256) void prep_kernel(
    const float* __restrict__ w1, const float* __restrict__ b1, const float* __restrict__ bn1,
    const float* __restrict__ w2, const float* __restrict__ b2, const float* __restrict__ bn2,
    const float* __restrict__ wg1, const float* __restrict__ bg1, const float* __restrict__ bng1,
    const float* __restrict__ wg2, const float* __restrict__ bg2, const float* __restrict__ bng2,
    const float* __restrict__ wf1, const float* __restrict__ bf1, const float* __restrict__ bnf1,
    const float* __restrict__ wf2, const float* __restrict__ bf2, const float* __restrict__ bnf2,
    f16* __restrict__ w1f, float* __restrict__ shift1,
    f16* __restrict__ w2f, float* __restrict__ shift2,
    f16* __restrict__ wg1f, float* __restrict__ shiftg1,
    f16* __restrict__ wg2f, float* __restrict__ shiftg2,
    f16* __restrict__ wf1f, float* __restrict__ shiftf1,
    f16* __restrict__ wf2f, float* __restrict__ shiftf2)
{
  int t = blockIdx.x*256 + threadIdx.x;
  if (t < 128*64){                       // chem L1: [128 cols][64 k], k>=34 zero
    int n = t>>6, k = t&63;
    float s = bn1[n]*rsqrtf(bn1[384+n]+EPSF);
    w1f[t] = (k<CI) ? (f16)(w1[k*128+n]*s) : (f16)0.f;
    if (k==0) shift1[n] = fmaf(s, b1[n]-bn1[256+n], bn1[128+n]);
  }
  if (t < 256*128){                      // chem L2: [256 cols][128 k]
    int n = t>>7, k = t&127;
    float s = bn2[n]*rsqrtf(bn2[768+n]+EPSF);
    w2f[t] = (f16)(w2[k*256+n]*s);
    if (k==0) shift2[n] = fmaf(s, b2[n]-bn2[512+n], bn2[256+n]);
  }
  if (t < 64*64){                        // geom L1: [64 cols][64 k], k>=48 zero
    int n = t>>6, k = t&63;
    float s = bng1[n]*rsqrtf(bng1[192+n]+EPSF);
    wg1f[t] = (k<GI) ? (f16)(wg1[k*64+n]*s) : (f16)0.f;
    if (k==0) shiftg1[n] = fmaf(s, bg1[n]-bng1[128+n], bng1[64+n]);
  }
  if (t < 64*64){                        // geom L2: [64 cols][64 k]
    int n = t>>6, k = t&63;
    float s = bng2[n]*rsqrtf(bng2[192+n]+EPSF);
    wg2f[t] = (f16)(wg2[k*64+n]*s);
    if (k==0) shiftg2[n] = fmaf(s, bg2[n]-bng2[128+n], bng2[64+n]);
  }
  if (t < 128*192){                      // feat L1: [128 cols][192 k]
    int n = t/192, k = t - n*192;
    float s = bnf1[n]*rsqrtf(bnf1[384+n]+EPSF);
    wf1f[t] = (f16)(wf1[k*128+n]*s);
    if (k==0) shiftf1[n] = fmaf(s, bf1[n]-bnf1[256+n], bnf1[128+n]);
  }
  if (t < 128*128){                      // feat L2: [128 cols][128 k]
    int n = t>>7, k = t&127;
    float s = bnf2[n]*rsqrtf(bnf2[384+n]+EPSF);
    wf2f[t] = (f16)(wf2[k*128+n]*s);
    if (k==0) shiftf2[n] = fmaf(s, bf2[n]-bnf2[256+n], bnf2[128+n]);
  }
}

// ---------------- counting sort of edges by vertex
__global__ __launch_bounds__(256) void hist_kernel(const int* __restrict__ vids, int* __restrict__ counts){
  int i = blockIdx.x*blockDim.x + threadIdx.x;
  int stride = gridDim.x*blockDim.x;
  for(; i<E_CNT; i+=stride) atomicAdd(&counts[vids[i]], 1);
}

__global__ __launch_bounds__(1024) void scan_kernel(const int* __restrict__ counts,
                                                    int* __restrict__ offsets,
                                                    int* __restrict__ offsets_work){
  __shared__ int ps[1024];
  const int t = threadIdx.x;
  int4 c[16]; int s = 0;
  const int4* cp = (const int4*)counts + (size_t)t*16;
  #pragma unroll
  for(int i=0;i<16;i++){ c[i]=cp[i]; s += c[i].x+c[i].y+c[i].z+c[i].w; }
  ps[t]=s; __syncthreads();
  for(int d=1; d<1024; d<<=1){
    int v = (t>=d) ? ps[t-d] : 0;
    __syncthreads();
    ps[t] += v;
    __syncthreads();
  }
  int run = ps[t]-s;     // exclusive prefix of this thread's 64-chunk
  int4* o1 = (int4*)offsets + (size_t)t*16;
  int4* o2 = (int4*)offsets_work + (size_t)t*16;
  #pragma unroll
  for(int i=0;i<16;i++){
    int4 cc=c[i]; int4 o;
    o.x=run; run+=cc.x; o.y=run; run+=cc.y; o.z=run; run+=cc.z; o.w=run; run+=cc.w;
    o1[i]=o; o2[i]=o;
  }
  if(t==1023) offsets[65536] = run;
}

__global__ __launch_bounds__(256) void scatter_kernel(const int* __restrict__ vids,
                                                      int* __restrict__ offsets_work,
                                                      int* __restrict__ perm){
  int i = blockIdx.x*blockDim.x + threadIdx.x;
  int stride = gridDim.x*blockDim.x;
  for(; i<E_CNT; i+=stride){
    int v = vids[i];
    int pos = atomicAdd(&offsets_work[v], 1);
    perm[pos] = i;
  }
}

// ---------------- geom MLP via MFMA: 64 vertices/block -> h_feat[V][192] cols 128..191 (f16)
__global__ __launch_bounds__(256) void geom_mfma(
    const float* __restrict__ geom,
    const f16* __restrict__ wg1f, const float* __restrict__ shg1,
    const f16* __restrict__ wg2f, const float* __restrict__ shg2,
    f16* __restrict__ h_feat)
{
  __shared__ __align__(16) f16 Ag[64][72];   // row 144B (+4 bank stagger)
  const int t = threadIdx.x, w = t>>6, lane = t&63, n16 = lane&15, quad = lane>>4;
  const int v0 = blockIdx.x*64;
  const int col = w*16 + n16;

  for(int i=t;i<64*GI;i+=256){ int r=i/GI, k=i-r*GI; Ag[r][k] = (f16)geom[(size_t)v0*GI + i]; }
  { uint* Aw=(uint*)Ag; for(int i=t;i<64*8;i+=256){ int r=i>>3; Aw[r*36+24+(i&7)]=0u; } }

  f16x8 bg1[2], bg2[2];
  #pragma unroll
  for(int ks=0;ks<2;ks++){
    bg1[ks] = *(const f16x8*)(wg1f + (size_t)col*64 + ks*32 + quad*8);
    bg2[ks] = *(const f16x8*)(wg2f + (size_t)col*64 + ks*32 + quad*8);
  }
  __syncthreads();

  f32x4 c1[4];
  #pragma unroll
  for(int mt=0;mt<4;mt++) c1[mt] = (f32x4)(0.f);
  #pragma unroll
  for(int mt=0;mt<4;mt++)
    #pragma unroll
    for(int ks=0;ks<2;ks++){
      f16x8 a = *(const f16x8*)(&Ag[mt*16+n16][ks*32+quad*8]);
      c1[mt] = MFMA16(a, bg1[ks], c1[mt]);
    }
  __syncthreads();   // all layer-1 reads done before overwriting Ag

  float s1 = shg1[col];
  #pragma unroll
  for(int mt=0;mt<4;mt++)
    #pragma unroll
    for(int r=0;r<4;r++)
      Ag[mt*16+quad*4+r][col] = (f16)siluf_(c1[mt][r] + s1);
  __syncthreads();

  f32x4 c2[4];
  #pragma unroll
  for(int mt=0;mt<4;mt++) c2[mt] = (f32x4)(0.f);
  #pragma unroll
  for(int mt=0;mt<4;mt++)
    #pragma unroll
    for(int ks=0;ks<2;ks++){
      f16x8 a = *(const f16x8*)(&Ag[mt*16+n16][ks*32+quad*8]);
      c2[mt] = MFMA16(a, bg2[ks], c2[mt]);
    }
  float s2 = shg2[col];
  #pragma unroll
  for(int mt=0;mt<4;mt++)
    #pragma unroll
    for(int r=0;r<4;r++)
      h_feat[(size_t)(v0 + mt*16+quad*4+r)*192 + 128 + col] = (f16)(c2[mt][r] + s2);
}

// ---------------- chem MLP over sorted edges; 4 vertices/block (exclusive ownership),
// LDS fp32 accumulate, plain f16 stores into h_feat cols 0..127. 16384 blocks.
__global__ __launch_bounds__(256) void chem_gather(
    const float* __restrict__ chem, const int* __restrict__ perm,
    const int* __restrict__ offsets,
    const f16* __restrict__ w1f, const float* __restrict__ shift1,
    const f16* __restrict__ w2f, const float* __restrict__ shift2,
    f16* __restrict__ h_feat)
{
  __shared__ __align__(16) f16 A1[64][72];     // 9216 B
  __shared__ __align__(16) f16 A2[64][136];    // 17408 B
  __shared__ float accs[VB][132];              // 2112 B (row pad: +4 banks)
  __shared__ int loff[VB+1];
  __shared__ int eidx[64];
  __shared__ __align__(16) int vloc[64];

  const int t = threadIdx.x, w = t>>6, lane = t&63, n16 = lane&15, quad = lane>>4;
  const int v0 = blockIdx.x*VB;

  if(t<VB+1) loff[t] = offsets[v0+t];
  for(int i=t;i<VB*132;i+=256) ((float*)accs)[i] = 0.f;

  // hoist B fragments (L2-resident)
  const int ntab[4] = {2*w, 2*w+1, 2*w+8, 2*w+9};
  f16x8 b2[4][4];
  #pragma unroll
  for(int p=0;p<4;p++){
    int col = ntab[p]*16 + n16;
    #pragma unroll
    for(int ks=0;ks<4;ks++)
      b2[p][ks] = *(const f16x8*)(w2f + (size_t)col*128 + ks*32 + quad*8);
  }
  f16x8 b1[2][2];
  #pragma unroll
  for(int p=0;p<2;p++){
    int col = (2*w+p)*16 + n16;
    #pragma unroll
    for(int ks=0;ks<2;ks++)
      b1[p][ks] = *(const f16x8*)(w1f + (size_t)col*64 + ks*32 + quad*8);
  }
  float sh1v[2], shf[2], shc[2];
  sh1v[0] = shift1[(2*w+0)*16 + n16];
  sh1v[1] = shift1[(2*w+1)*16 + n16];
  shf[0] = shift2[(2*w+0)*16 + n16];
  shf[1] = shift2[(2*w+1)*16 + n16];
  shc[0] = shift2[128 + (2*w+0)*16 + n16];
  shc[1] = shift2[128 + (2*w+1)*16 + n16];
  __syncthreads();   // loff ready, accs zeroed

  const int base = loff[0];
  const int nE = loff[VB] - base;

  for(int tile=0; tile*64 < nE; ++tile){
    if(tile) __syncthreads();              // prev iter consumed vloc / finished accs adds
    if(t<64){
      int p = base + tile*64 + t;
      if(p < base + nE){
        eidx[t] = perm[p];
        vloc[t] = ((p>=loff[1])?1:0) + ((p>=loff[2])?1:0) + ((p>=loff[3])?1:0);
      } else { eidx[t] = -1; vloc[t] = -1; }
    }
    __syncthreads();
    { // stage A1: float2 gathers -> packed f16 pairs; zero pad k 34..63
      uint* A1w = (uint*)A1;
      for(int i=t;i<64*19;i+=256){ int r=i/19, wd=17+(i-r*19); A1w[r*36+wd]=0u; }
      for(int i=t;i<64*17;i+=256){
        int e=i/17, k2=i-e*17; int ed = eidx[e];
        union { f16 h[2]; uint u; } pk;
        if(ed>=0){
          float2 v = *(const float2*)(chem + (size_t)ed*CI + 2*k2);
          pk.h[0]=(f16)v.x; pk.h[1]=(f16)v.y;
        } else pk.u = 0u;
        A1w[e*36 + k2] = pk.u;
      }
    }
    __syncthreads();

    // layer 1
    f32x4 c1[4][2];
    #pragma unroll
    for(int mt=0;mt<4;mt++){ c1[mt][0]=(f32x4)(0.f); c1[mt][1]=(f32x4)(0.f); }
    #pragma unroll
    for(int mt=0;mt<4;mt++)
      #pragma unroll
      for(int ks=0;ks<2;ks++){
        f16x8 a = *(const f16x8*)(&A1[mt*16+n16][ks*32+quad*8]);
        #pragma unroll
        for(int p=0;p<2;p++) c1[mt][p] = MFMA16(a, b1[p][ks], c1[mt][p]);
      }
    #pragma unroll
    for(int mt=0;mt<4;mt++)
      #pragma unroll
      for(int p=0;p<2;p++){
        int col = (2*w+p)*16 + n16;
        #pragma unroll
        for(int r=0;r<4;r++)
          A2[mt*16+quad*4+r][col] = (f16)siluf_(c1[mt][p][r] + sh1v[p]);
      }
    __syncthreads();

    // layer 2
    f32x4 c2[4][4];
    #pragma unroll
    for(int mt=0;mt<4;mt++)
      #pragma unroll
      for(int p=0;p<4;p++) c2[mt][p] = (f32x4)(0.f);
    #pragma unroll
    for(int ks=0;ks<4;ks++){
      f16x8 a[4];
      #pragma unroll
      for(int mt=0;mt<4;mt++)
        a[mt] = *(const f16x8*)(&A2[mt*16+n16][ks*32+quad*8]);
      #pragma unroll
      for(int mt=0;mt<4;mt++)
        #pragma unroll
        for(int p=0;p<4;p++)
          c2[mt][p] = MFMA16(a[mt], b2[p][ks], c2[mt][p]);
    }

    // gate + LDS accumulate
    #pragma unroll
    for(int mt=0;mt<4;mt++){
      int4 vv = *(const int4*)&vloc[mt*16 + quad*4];
      int vls[4] = {vv.x, vv.y, vv.z, vv.w};
      #pragma unroll
      for(int p=0;p<2;p++){
        int colf = (2*w+p)*16 + n16;
        #pragma unroll
        for(int r=0;r<4;r++){
          int vl = vls[r];
          if(vl >= 0){
            float f  = sigmoidf_(c2[mt][p][r]   + shf[p]);
            float cc = softplusf_(c2[mt][p+2][r] + shc[p]);
            atomicAdd(&accs[vl][colf], f*cc);
          }
        }
      }
    }
  }
  __syncthreads();
  // write VB vertex rows as f16 into h_feat cols 0..127
  for(int i=t;i<VB*128;i+=256){
    int r=i>>7, c=i&127;
    h_feat[(size_t)(v0+r)*192 + c] = (f16)accs[r][c];
  }
}

// ---------------- feat MLP via MFMA: 64 vertices/block, input h_feat[V][192] f16 -> out [V,128] f32
__global__ __launch_bounds__(256) void feat_mfma(
    const f16* __restrict__ h_feat,
    const f16* __restrict__ wf1f, const float* __restrict__ shf1,
    const f16* __restrict__ wf2f, const float* __restrict__ shf2,
    float* __restrict__ out)
{
  __shared__ __align__(16) f16 Af[64][200];   // row 400B (stagger), K=192
  const int t = threadIdx.x, w = t>>6, lane = t&63, n16 = lane&15, quad = lane>>4;
  const int v0 = blockIdx.x*64;

  // contiguous 384B/row uint4 copy
  for(int i=t;i<64*24;i+=256){
    int r=i/24, c=i-r*24;
    ((uint4*)&Af[r][0])[c] = ((const uint4*)(h_feat + (size_t)(v0+r)*192))[c];
  }

  f16x8 B1[2][6];
  #pragma unroll
  for(int p=0;p<2;p++){
    int col = (2*w+p)*16 + n16;
    #pragma unroll
    for(int ks=0;ks<6;ks++)
      B1[p][ks] = *(const f16x8*)(wf1f + (size_t)col*192 + ks*32 + quad*8);
  }
  __syncthreads();

  f32x4 c1[4][2];
  #pragma unroll
  for(int mt=0;mt<4;mt++){ c1[mt][0]=(f32x4)(0.f); c1[mt][1]=(f32x4)(0.f); }
  #pragma unroll
  for(int ks=0;ks<6;ks++){
    f16x8 a[4];
    #pragma unroll
    for(int mt=0;mt<4;mt++)
      a[mt] = *(const f16x8*)(&Af[mt*16+n16][ks*32+quad*8]);
    #pragma unroll
    for(int mt=0;mt<4;mt++)
      #pragma unroll
      for(int p=0;p<2;p++) c1[mt][p] = MFMA16(a[mt], B1[p][ks], c1[mt][p]);
  }
  __syncthreads();   // all layer-1 reads done

  float s1v[2] = { shf1[(2*w+0)*16+n16], shf1[(2*w+1)*16+n16] };
  #pragma unroll
  for(int mt=0;mt<4;mt++)
    #pragma unroll
    for(int p=0;p<2;p++){
      int col = (2*w+p)*16 + n16;
      #pragma unroll
      for(int r=0;r<4;r++)
        Af[mt*16+quad*4+r][col] = (f16)siluf_(c1[mt][p][r] + s1v[p]);
    }
  __syncthreads();

  f16x8 B2[2][4];
  #pragma unroll
  for(int p=0;p<2;p++){
    int col = (2*w+p)*16 + n16;
    #pragma unroll
    for(int ks=0;ks<4;ks++)
      B2[p][ks] = *(const f16x8*)(wf2f + (size_t)col*128 + ks*32 + quad*8);
  }
  f32x4 c2[4][2];
  #pragma unroll
  for(int mt=0;mt<4;mt++){ c2[mt][0]=(f32x4)(0.f); c2[mt][1]=(f32x4)(0.f); }
  #pragma unroll
  for(int ks=0;ks<4;ks++){
    f16x8 a[4];
    #pragma unroll
    for(int mt=0;mt<4;mt++)
      a[mt] = *(const f16x8*)(&Af[mt*16+n16][ks*32+quad*8]);
    #pragma unroll
    for(int mt=0;mt<4;mt++)
      #pragma unroll
      for(int p=0;p<2;p++) c2[mt][p] = MFMA16(a[mt], B2[p][ks], c2[mt][p]);
  }
  float s2v[2] = { shf2[(2*w+0)*16+n16], shf2[(2*w+1)*16+n16] };
  #pragma unroll
  for(int mt=0;mt<4;mt++)
    #pragma unroll
    for(int p=0;p<2;p++){
      int col = (2*w+p)*16 + n16;
      #pragma unroll
      for(int r=0;r<4;r++)
        out[(size_t)(v0 + mt*16+quad*4+r)*128 + col] = c2[mt][p][r] + s2v[p];
    }
}

extern "C" void kernel_launch(void* const* d_in, const int* in_sizes, int n_in,
                              void* d_out, int out_size, void* d_ws, size_t ws_size,
                              hipStream_t stream) {
  const float* chem = (const float*)d_in[0];
  const float* geom = (const float*)d_in[1];
  const int*   vids = (const int*)d_in[2];
  const float* w1  = (const float*)d_in[3];
  const float* b1  = (const float*)d_in[4];
  const float* bn1 = (const float*)d_in[5];
  const float* w2  = (const float*)d_in[6];
  const float* b2  = (const float*)d_in[7];
  const float* bn2 = (const float*)d_in[8];
  const float* wg1 = (const float*)d_in[9];
  const float* bg1 = (const float*)d_in[10];
  const float* bng1= (const float*)d_in[11];
  const float* wg2 = (const float*)d_in[12];
  const float* bg2 = (const float*)d_in[13];
  const float* bng2= (const float*)d_in[14];
  const float* wf1 = (const float*)d_in[15];
  const float* bf1 = (const float*)d_in[16];
  const float* bnf1= (const float*)d_in[17];
  const float* wf2 = (const float*)d_in[18];
  const float* bf2 = (const float*)d_in[19];
  const float* bnf2= (const float*)d_in[20];

  char* ws = (char*)d_ws;
  f16*   h_feat      = (f16*)  (ws + 0);             // V*192*2 = 25165824
  int*   perm        = (int*)  (ws + 25165824);      // 4194304
  int*   counts      = (int*)  (ws + 29360128);      // 262144
  int*   offsets     = (int*)  (ws + 29622272);      // 262400 (65537 ints, padded)
  int*   offsets_wk  = (int*)  (ws + 29884672);      // 262144
  f16*   w1f         = (f16*)  (ws + 30146816);      // 16384
  f16*   w2f         = (f16*)  (ws + 30163200);      // 65536
  f16*   wg1f        = (f16*)  (ws + 30228736);      // 8192
  f16*   wg2f        = (f16*)  (ws + 30236928);      // 8192
  f16*   wf1f        = (f16*)  (ws + 30245120);      // 49152
  f16*   wf2f        = (f16*)  (ws + 30294272);      // 32768
  float* shift1      = (float*)(ws + 30327040);      // 512
  float* shift2      = (float*)(ws + 30327552);      // 1024
  float* shiftg1     = (float*)(ws + 30328576);      // 256
  float* shiftg2     = (float*)(ws + 30328832);      // 256
  float* shiftf1     = (float*)(ws + 30329088);      // 512
  float* shiftf2     = (float*)(ws + 30329600);      // 512
  float* out         = (float*)d_out;

  hipMemsetAsync(counts, 0, 65536*sizeof(int), stream);
  prep_kernel<<<dim3(128), dim3(256), 0, stream>>>(
      w1,b1,bn1, w2,b2,bn2, wg1,bg1,bng1, wg2,bg2,bng2, wf1,bf1,bnf1, wf2,bf2,bnf2,
      w1f,shift1, w2f,shift2, wg1f,shiftg1, wg2f,shiftg2, wf1f,shiftf1, wf2f,shiftf2);
  hist_kernel<<<dim3(1024), dim3(256), 0, stream>>>(vids, counts);
  scan_kernel<<<dim3(1), dim3(1024), 0, stream>>>(counts, offsets, offsets_wk);
  scatter_kernel<<<dim3(1024), dim3(256), 0, stream>>>(vids, offsets_wk, perm);
  geom_mfma<<<dim3(V_CNT/64), dim3(256), 0, stream>>>(geom, wg1f,shiftg1, wg2f,shiftg2, h_feat);
  chem_gather<<<dim3(V_CNT/VB), dim3(256), 0, stream>>>(chem, perm, offsets, w1f,shift1, w2f,shift2, h_feat);
  feat_mfma<<<dim3(V_CNT/64), dim3(256), 0, stream>>>(h_feat, wf1f,shiftf1, wf2f,shiftf2, out);
}

// Round 5
// 886.135 us; speedup vs baseline: 1.5817x; 1.5817x over previous
//
#include <hip/hip_runtime.h>
#include <cstddef>

constexpr int V_CNT = 65536;
constexpr int E_CNT = 1048576;
constexpr int H_DIM = 128;
constexpr int CI = 34;   // chem in
constexpr int GI = 48;   // geom in
#define EPSF 1e-5f

typedef _Float16 f16;
typedef f16 f16x8 __attribute__((ext_vector_type(8)));
typedef float f32x4 __attribute__((ext_vector_type(4)));
#define MFMA16(a,b,c) __builtin_amdgcn_mfma_f32_16x16x32_f16(a,b,c,0,0,0)

__device__ __forceinline__ float sigmoidf_(float x){ return 1.0f/(1.0f+__expf(-x)); }
__device__ __forceinline__ float siluf_(float x){ return x/(1.0f+__expf(-x)); }
__device__ __forceinline__ float softplusf_(float x){
  return fmaxf(x,0.0f) + __logf(1.0f + __expf(-fabsf(x)));
}
__device__ __forceinline__ void fma4(float4& a, float s, float4 w){
  a.x = fmaf(s,w.x,a.x); a.y = fmaf(s,w.y,a.y);
  a.z = fmaf(s,w.z,a.z); a.w = fmaf(s,w.w,a.w);
}

// ---------------- prep: fold BN scale into all weights, convert to f16 col-major [col][k]
__global__ __launch_bounds__(256) void prep_kernel(
    const float* __restrict__ w1, const float* __restrict__ b1, const float* __restrict__ bn1,
    const float* __restrict__ w2, const float* __restrict__ b2, const float* __restrict__ bn2,
    const float* __restrict__ wg1, const float* __restrict__ bg1, const float* __restrict__ bng1,
    const float* __restrict__ wg2, const float* __restrict__ bg2, const float* __restrict__ bng2,
    const float* __restrict__ wf1, const float* __restrict__ bf1, const float* __restrict__ bnf1,
    const float* __restrict__ wf2, const float* __restrict__ bf2, const float* __restrict__ bnf2,
    f16* __restrict__ w1f, float* __restrict__ shift1,
    f16* __restrict__ w2f, float* __restrict__ shift2,
    f16* __restrict__ wg1f, float* __restrict__ shiftg1,
    f16* __restrict__ wg2f, float* __restrict__ shiftg2,
    f16* __restrict__ wf1f, float* __restrict__ shiftf1,
    f16* __restrict__ wf2f, float* __restrict__ shiftf2)
{
  int t = blockIdx.x*256 + threadIdx.x;
  if (t < 128*64){                       // chem L1: [128 cols][64 k], k>=34 zero
    int n = t>>6, k = t&63;
    float s = bn1[n]*rsqrtf(bn1[384+n]+EPSF);
    w1f[t] = (k<CI) ? (f16)(w1[k*128+n]*s) : (f16)0.f;
    if (k==0) shift1[n] = fmaf(s, b1[n]-bn1[256+n], bn1[128+n]);
  }
  if (t < 256*128){                      // chem L2: [256 cols][128 k]
    int n = t>>7, k = t&127;
    float s = bn2[n]*rsqrtf(bn2[768+n]+EPSF);
    w2f[t] = (f16)(w2[k*256+n]*s);
    if (k==0) shift2[n] = fmaf(s, b2[n]-bn2[512+n], bn2[256+n]);
  }
  if (t < 64*64){                        // geom L1: [64 cols][64 k], k>=48 zero
    int n = t>>6, k = t&63;
    float s = bng1[n]*rsqrtf(bng1[192+n]+EPSF);
    wg1f[t] = (k<GI) ? (f16)(wg1[k*64+n]*s) : (f16)0.f;
    if (k==0) shiftg1[n] = fmaf(s, bg1[n]-bng1[128+n], bng1[64+n]);
  }
  if (t < 64*64){                        // geom L2: [64 cols][64 k]
    int n = t>>6, k = t&63;
    float s = bng2[n]*rsqrtf(bng2[192+n]+EPSF);
    wg2f[t] = (f16)(wg2[k*64+n]*s);
    if (k==0) shiftg2[n] = fmaf(s, bg2[n]-bng2[128+n], bng2[64+n]);
  }
  if (t < 128*192){                      // feat L1: [128 cols][192 k]
    int n = t/192, k = t - n*192;
    float s = bnf1[n]*rsqrtf(bnf1[384+n]+EPSF);
    wf1f[t] = (f16)(wf1[k*128+n]*s);
    if (k==0) shiftf1[n] = fmaf(s, bf1[n]-bnf1[256+n], bnf1[128+n]);
  }
  if (t < 128*128){                      // feat L2: [128 cols][128 k]
    int n = t>>7, k = t&127;
    float s = bnf2[n]*rsqrtf(bnf2[384+n]+EPSF);
    wf2f[t] = (f16)(wf2[k*128+n]*s);
    if (k==0) shiftf2[n] = fmaf(s, bf2[n]-bnf2[256+n], bnf2[128+n]);
  }
}

// ---------------- counting sort of edges by vertex
__global__ __launch_bounds__(256) void hist_kernel(const int* __restrict__ vids, int* __restrict__ counts){
  int i = blockIdx.x*blockDim.x + threadIdx.x;
  int stride = gridDim.x*blockDim.x;
  for(; i<E_CNT; i+=stride) atomicAdd(&counts[vids[i]], 1);
}

__global__ __launch_bounds__(1024) void scan_kernel(const int* __restrict__ counts,
                                                    int* __restrict__ offsets,
                                                    int* __restrict__ offsets_work){
  __shared__ int ps[1024];
  const int t = threadIdx.x;
  int4 c[16]; int s = 0;
  const int4* cp = (const int4*)counts + (size_t)t*16;
  #pragma unroll
  for(int i=0;i<16;i++){ c[i]=cp[i]; s += c[i].x+c[i].y+c[i].z+c[i].w; }
  ps[t]=s; __syncthreads();
  for(int d=1; d<1024; d<<=1){
    int v = (t>=d) ? ps[t-d] : 0;
    __syncthreads();
    ps[t] += v;
    __syncthreads();
  }
  int run = ps[t]-s;
  int4* o1 = (int4*)offsets + (size_t)t*16;
  int4* o2 = (int4*)offsets_work + (size_t)t*16;
  #pragma unroll
  for(int i=0;i<16;i++){
    int4 cc=c[i]; int4 o;
    o.x=run; run+=cc.x; o.y=run; run+=cc.y; o.z=run; run+=cc.z; o.w=run; run+=cc.w;
    o1[i]=o; o2[i]=o;
  }
  if(t==1023) offsets[65536] = run;
}

__global__ __launch_bounds__(256) void scatter_kernel(const int* __restrict__ vids,
                                                      int* __restrict__ offsets_work,
                                                      int* __restrict__ perm){
  int i = blockIdx.x*blockDim.x + threadIdx.x;
  int stride = gridDim.x*blockDim.x;
  for(; i<E_CNT; i+=stride){
    int v = vids[i];
    int pos = atomicAdd(&offsets_work[v], 1);
    perm[pos] = i;
  }
}

// ---------------- geom MLP via MFMA: 64 vertices/block -> dst[(v)*stride + colbase + col] (f16)
__global__ __launch_bounds__(256) void geom_mfma(
    const float* __restrict__ geom,
    const f16* __restrict__ wg1f, const float* __restrict__ shg1,
    const f16* __restrict__ wg2f, const float* __restrict__ shg2,
    f16* __restrict__ dst, int stride, int colbase)
{
  __shared__ __align__(16) f16 Ag[64][72];
  const int t = threadIdx.x, w = t>>6, lane = t&63, n16 = lane&15, quad = lane>>4;
  const int v0 = blockIdx.x*64;
  const int col = w*16 + n16;

  for(int i=t;i<64*GI;i+=256){ int r=i/GI, k=i-r*GI; Ag[r][k] = (f16)geom[(size_t)v0*GI + i]; }
  { uint* Aw=(uint*)Ag; for(int i=t;i<64*8;i+=256){ int r=i>>3; Aw[r*36+24+(i&7)]=0u; } }

  f16x8 bg1[2], bg2[2];
  #pragma unroll
  for(int ks=0;ks<2;ks++){
    bg1[ks] = *(const f16x8*)(wg1f + (size_t)col*64 + ks*32 + quad*8);
    bg2[ks] = *(const f16x8*)(wg2f + (size_t)col*64 + ks*32 + quad*8);
  }
  __syncthreads();

  f32x4 c1[4];
  #pragma unroll
  for(int mt=0;mt<4;mt++) c1[mt] = (f32x4)(0.f);
  #pragma unroll
  for(int mt=0;mt<4;mt++)
    #pragma unroll
    for(int ks=0;ks<2;ks++){
      f16x8 a = *(const f16x8*)(&Ag[mt*16+n16][ks*32+quad*8]);
      c1[mt] = MFMA16(a, bg1[ks], c1[mt]);
    }
  __syncthreads();

  float s1 = shg1[col];
  #pragma unroll
  for(int mt=0;mt<4;mt++)
    #pragma unroll
    for(int r=0;r<4;r++)
      Ag[mt*16+quad*4+r][col] = (f16)siluf_(c1[mt][r] + s1);
  __syncthreads();

  f32x4 c2[4];
  #pragma unroll
  for(int mt=0;mt<4;mt++) c2[mt] = (f32x4)(0.f);
  #pragma unroll
  for(int mt=0;mt<4;mt++)
    #pragma unroll
    for(int ks=0;ks<2;ks++){
      f16x8 a = *(const f16x8*)(&Ag[mt*16+n16][ks*32+quad*8]);
      c2[mt] = MFMA16(a, bg2[ks], c2[mt]);
    }
  float s2 = shg2[col];
  #pragma unroll
  for(int mt=0;mt<4;mt++)
    #pragma unroll
    for(int r=0;r<4;r++)
      dst[(size_t)(v0 + mt*16+quad*4+r)*stride + colbase + col] = (f16)(c2[mt][r] + s2);
}

// ---------------- PHASE A: streaming chem MLP, original edge order, gated f16 out [E][128]
// 64 edges/block, 16384 blocks, ONE barrier, A-fragments direct from global.
__global__ __launch_bounds__(256) void chem_dense(
    const float* __restrict__ chem,
    const f16* __restrict__ w1f, const float* __restrict__ shift1,
    const f16* __restrict__ w2f, const float* __restrict__ shift2,
    f16* __restrict__ gated)
{
  __shared__ __align__(16) f16 A2[64][136];   // 17408 B
  const int t = threadIdx.x, w = t>>6, lane = t&63, n16 = lane&15, quad = lane>>4;
  const long e0 = (long)blockIdx.x*64;

  // layer-1 B fragments
  f16x8 b1[2][2];
  #pragma unroll
  for(int p=0;p<2;p++){
    int col = (2*w+p)*16 + n16;
    #pragma unroll
    for(int ks=0;ks<2;ks++)
      b1[p][ks] = *(const f16x8*)(w1f + (size_t)col*64 + ks*32 + quad*8);
  }
  float sh1v[2];
  sh1v[0] = shift1[(2*w+0)*16 + n16];
  sh1v[1] = shift1[(2*w+1)*16 + n16];

  // layer 1: A fragments straight from global (row-major fp32 -> f16 regs)
  f32x4 c1[4][2];
  #pragma unroll
  for(int mt=0;mt<4;mt++){ c1[mt][0]=(f32x4)(0.f); c1[mt][1]=(f32x4)(0.f); }
  #pragma unroll
  for(int mt=0;mt<4;mt++){
    const float* base = chem + (size_t)(e0 + mt*16 + n16)*CI;
    float2 u0 = *(const float2*)(base + quad*8 + 0);
    float2 u1 = *(const float2*)(base + quad*8 + 2);
    float2 u2 = *(const float2*)(base + quad*8 + 4);
    float2 u3 = *(const float2*)(base + quad*8 + 6);
    f16x8 a0;
    a0[0]=(f16)u0.x; a0[1]=(f16)u0.y; a0[2]=(f16)u1.x; a0[3]=(f16)u1.y;
    a0[4]=(f16)u2.x; a0[5]=(f16)u2.y; a0[6]=(f16)u3.x; a0[7]=(f16)u3.y;
    f16x8 a1 = (f16x8)(f16)0.f;
    if(quad==0){
      float2 uT = *(const float2*)(base + 32);
      a1[0]=(f16)uT.x; a1[1]=(f16)uT.y;
    }
    #pragma unroll
    for(int p=0;p<2;p++){
      c1[mt][p] = MFMA16(a0, b1[p][0], c1[mt][p]);
      c1[mt][p] = MFMA16(a1, b1[p][1], c1[mt][p]);
    }
  }
  // activation -> A2 (transpose C->A layout via LDS)
  #pragma unroll
  for(int mt=0;mt<4;mt++)
    #pragma unroll
    for(int p=0;p<2;p++){
      int col = (2*w+p)*16 + n16;
      #pragma unroll
      for(int r=0;r<4;r++)
        A2[mt*16+quad*4+r][col] = (f16)siluf_(c1[mt][p][r] + sh1v[p]);
    }

  // layer-2 B fragments (load before barrier to hide latency)
  const int ntab[4] = {2*w, 2*w+1, 2*w+8, 2*w+9};
  f16x8 b2[4][4];
  #pragma unroll
  for(int p=0;p<4;p++){
    int col = ntab[p]*16 + n16;
    #pragma unroll
    for(int ks=0;ks<4;ks++)
      b2[p][ks] = *(const f16x8*)(w2f + (size_t)col*128 + ks*32 + quad*8);
  }
  float shf[2], shc[2];
  shf[0] = shift2[(2*w+0)*16 + n16];
  shf[1] = shift2[(2*w+1)*16 + n16];
  shc[0] = shift2[128 + (2*w+0)*16 + n16];
  shc[1] = shift2[128 + (2*w+1)*16 + n16];
  __syncthreads();

  // layer 2
  f32x4 c2[4][4];
  #pragma unroll
  for(int mt=0;mt<4;mt++)
    #pragma unroll
    for(int p=0;p<4;p++) c2[mt][p] = (f32x4)(0.f);
  #pragma unroll
  for(int ks=0;ks<4;ks++){
    f16x8 a[4];
    #pragma unroll
    for(int mt=0;mt<4;mt++)
      a[mt] = *(const f16x8*)(&A2[mt*16+n16][ks*32+quad*8]);
    #pragma unroll
    for(int mt=0;mt<4;mt++)
      #pragma unroll
      for(int p=0;p<4;p++)
        c2[mt][p] = MFMA16(a[mt], b2[p][ks], c2[mt][p]);
  }

  // gate + plain f16 stores (lanes n16 -> 32B dense segments)
  #pragma unroll
  for(int mt=0;mt<4;mt++){
    #pragma unroll
    for(int p=0;p<2;p++){
      int colf = (2*w+p)*16 + n16;
      #pragma unroll
      for(int r=0;r<4;r++){
        long e = e0 + mt*16 + quad*4 + r;
        float f  = sigmoidf_(c2[mt][p][r]   + shf[p]);
        float cc = softplusf_(c2[mt][p+2][r] + shc[p]);
        gated[(size_t)e*H_DIM + colf] = (f16)(f*cc);
      }
    }
  }
}

// ---------------- PHASE B: sorted segment-sum of gated rows -> h_feat cols 0..127
// 8 vertices/block (4 groups of 64 lanes x 2 vertices), coalesced 256B row reads.
__global__ __launch_bounds__(256) void chem_agg(
    const f16* __restrict__ gated, const int* __restrict__ perm,
    const int* __restrict__ offsets, f16* __restrict__ h_feat)
{
  __shared__ int loff[9];
  const int t = threadIdx.x, g = t>>6, l = t&63;
  const int v0 = blockIdx.x*8;
  if(t<9) loff[t] = offsets[v0+t];
  __syncthreads();

  #pragma unroll
  for(int vi=0; vi<2; ++vi){
    int vv = g*2 + vi;
    int s = loff[vv], e = loff[vv+1];
    float a0 = 0.f, a1 = 0.f;
    int p = s;
    for(; p+1 < e; p += 2){
      int i0 = perm[p], i1 = perm[p+1];
      uint u0 = *(const uint*)(gated + (size_t)i0*H_DIM + 2*l);
      uint u1 = *(const uint*)(gated + (size_t)i1*H_DIM + 2*l);
      union { uint u; f16 h[2]; } q0, q1;
      q0.u = u0; q1.u = u1;
      a0 += (float)q0.h[0] + (float)q1.h[0];
      a1 += (float)q0.h[1] + (float)q1.h[1];
    }
    if(p < e){
      int i0 = perm[p];
      union { uint u; f16 h[2]; } q0;
      q0.u = *(const uint*)(gated + (size_t)i0*H_DIM + 2*l);
      a0 += (float)q0.h[0];
      a1 += (float)q0.h[1];
    }
    union { uint u; f16 h[2]; } pk;
    pk.h[0] = (f16)a0; pk.h[1] = (f16)a1;
    *(uint*)(h_feat + (size_t)(v0+vv)*192 + 2*l) = pk.u;
  }
}

// ---------------- feat MLP (big path): h_feat[V][192] f16 -> out [V,128] f32
__global__ __launch_bounds__(256) void feat_mfma(
    const f16* __restrict__ h_feat,
    const f16* __restrict__ wf1f, const float* __restrict__ shf1,
    const f16* __restrict__ wf2f, const float* __restrict__ shf2,
    float* __restrict__ out)
{
  __shared__ __align__(16) f16 Af[64][200];
  const int t = threadIdx.x, w = t>>6, lane = t&63, n16 = lane&15, quad = lane>>4;
  const int v0 = blockIdx.x*64;

  for(int i=t;i<64*24;i+=256){
    int r=i/24, c=i-r*24;
    ((uint4*)&Af[r][0])[c] = ((const uint4*)(h_feat + (size_t)(v0+r)*192))[c];
  }

  f16x8 B1[2][6];
  #pragma unroll
  for(int p=0;p<2;p++){
    int col = (2*w+p)*16 + n16;
    #pragma unroll
    for(int ks=0;ks<6;ks++)
      B1[p][ks] = *(const f16x8*)(wf1f + (size_t)col*192 + ks*32 + quad*8);
  }
  __syncthreads();

  f32x4 c1[4][2];
  #pragma unroll
  for(int mt=0;mt<4;mt++){ c1[mt][0]=(f32x4)(0.f); c1[mt][1]=(f32x4)(0.f); }
  #pragma unroll
  for(int ks=0;ks<6;ks++){
    f16x8 a[4];
    #pragma unroll
    for(int mt=0;mt<4;mt++)
      a[mt] = *(const f16x8*)(&Af[mt*16+n16][ks*32+quad*8]);
    #pragma unroll
    for(int mt=0;mt<4;mt++)
      #pragma unroll
      for(int p=0;p<2;p++) c1[mt][p] = MFMA16(a[mt], B1[p][ks], c1[mt][p]);
  }
  __syncthreads();

  float s1v[2] = { shf1[(2*w+0)*16+n16], shf1[(2*w+1)*16+n16] };
  #pragma unroll
  for(int mt=0;mt<4;mt++)
    #pragma unroll
    for(int p=0;p<2;p++){
      int col = (2*w+p)*16 + n16;
      #pragma unroll
      for(int r=0;r<4;r++)
        Af[mt*16+quad*4+r][col] = (f16)siluf_(c1[mt][p][r] + s1v[p]);
    }
  __syncthreads();

  f16x8 B2[2][4];
  #pragma unroll
  for(int p=0;p<2;p++){
    int col = (2*w+p)*16 + n16;
    #pragma unroll
    for(int ks=0;ks<4;ks++)
      B2[p][ks] = *(const f16x8*)(wf2f + (size_t)col*128 + ks*32 + quad*8);
  }
  f32x4 c2[4][2];
  #pragma unroll
  for(int mt=0;mt<4;mt++){ c2[mt][0]=(f32x4)(0.f); c2[mt][1]=(f32x4)(0.f); }
  #pragma unroll
  for(int ks=0;ks<4;ks++){
    f16x8 a[4];
    #pragma unroll
    for(int mt=0;mt<4;mt++)
      a[mt] = *(const f16x8*)(&Af[mt*16+n16][ks*32+quad*8]);
    #pragma unroll
    for(int mt=0;mt<4;mt++)
      #pragma unroll
      for(int p=0;p<2;p++) c2[mt][p] = MFMA16(a[mt], B2[p][ks], c2[mt][p]);
  }
  float s2v[2] = { shf2[(2*w+0)*16+n16], shf2[(2*w+1)*16+n16] };
  #pragma unroll
  for(int mt=0;mt<4;mt++)
    #pragma unroll
    for(int p=0;p<2;p++){
      int col = (2*w+p)*16 + n16;
      #pragma unroll
      for(int r=0;r<4;r++)
        out[(size_t)(v0 + mt*16+quad*4+r)*128 + col] = c2[mt][p][r] + s2v[p];
    }
}

// ================= FALLBACK PATH (small ws): r2-style atomic chem =================
__global__ __launch_bounds__(256) void zero_f4(float4* p, int n4){
  int i = blockIdx.x*blockDim.x + threadIdx.x;
  int stride = gridDim.x*blockDim.x;
  float4 z; z.x=0.f; z.y=0.f; z.z=0.f; z.w=0.f;
  for(; i<n4; i+=stride) p[i] = z;
}

__global__ __launch_bounds__(256) void chem_atomic(
    const float* __restrict__ chem, const int* __restrict__ vids,
    const f16* __restrict__ w1f, const float* __restrict__ shift1,
    const f16* __restrict__ w2f, const float* __restrict__ shift2,
    float* __restrict__ h_chem)
{
  __shared__ __align__(16) f16 A2[64][136];
  __shared__ __align__(16) int vid_s[64];
  const int t = threadIdx.x, w = t>>6, lane = t&63, n16 = lane&15, quad = lane>>4;
  const long e0 = (long)blockIdx.x*64;

  if(t<64) vid_s[t] = vids[e0+t];

  f16x8 b1[2][2];
  #pragma unroll
  for(int p=0;p<2;p++){
    int col = (2*w+p)*16 + n16;
    #pragma unroll
    for(int ks=0;ks<2;ks++)
      b1[p][ks] = *(const f16x8*)(w1f + (size_t)col*64 + ks*32 + quad*8);
  }
  float sh1v[2] = { shift1[(2*w+0)*16+n16], shift1[(2*w+1)*16+n16] };

  f32x4 c1[4][2];
  #pragma unroll
  for(int mt=0;mt<4;mt++){ c1[mt][0]=(f32x4)(0.f); c1[mt][1]=(f32x4)(0.f); }
  #pragma unroll
  for(int mt=0;mt<4;mt++){
    const float* base = chem + (size_t)(e0 + mt*16 + n16)*CI;
    float2 u0 = *(const float2*)(base + quad*8 + 0);
    float2 u1 = *(const float2*)(base + quad*8 + 2);
    float2 u2 = *(const float2*)(base + quad*8 + 4);
    float2 u3 = *(const float2*)(base + quad*8 + 6);
    f16x8 a0;
    a0[0]=(f16)u0.x; a0[1]=(f16)u0.y; a0[2]=(f16)u1.x; a0[3]=(f16)u1.y;
    a0[4]=(f16)u2.x; a0[5]=(f16)u2.y; a0[6]=(f16)u3.x; a0[7]=(f16)u3.y;
    f16x8 a1 = (f16x8)(f16)0.f;
    if(quad==0){
      float2 uT = *(const float2*)(base + 32);
      a1[0]=(f16)uT.x; a1[1]=(f16)uT.y;
    }
    #pragma unroll
    for(int p=0;p<2;p++){
      c1[mt][p] = MFMA16(a0, b1[p][0], c1[mt][p]);
      c1[mt][p] = MFMA16(a1, b1[p][1], c1[mt][p]);
    }
  }
  #pragma unroll
  for(int mt=0;mt<4;mt++)
    #pragma unroll
    for(int p=0;p<2;p++){
      int col = (2*w+p)*16 + n16;
      #pragma unroll
      for(int r=0;r<4;r++)
        A2[mt*16+quad*4+r][col] = (f16)siluf_(c1[mt][p][r] + sh1v[p]);
    }
  const int ntab[4] = {2*w, 2*w+1, 2*w+8, 2*w+9};
  f16x8 b2[4][4];
  #pragma unroll
  for(int p=0;p<4;p++){
    int col = ntab[p]*16 + n16;
    #pragma unroll
    for(int ks=0;ks<4;ks++)
      b2[p][ks] = *(const f16x8*)(w2f + (size_t)col*128 + ks*32 + quad*8);
  }
  float shf[2] = { shift2[(2*w+0)*16+n16], shift2[(2*w+1)*16+n16] };
  float shc[2] = { shift2[128+(2*w+0)*16+n16], shift2[128+(2*w+1)*16+n16] };
  __syncthreads();

  f32x4 c2[4][4];
  #pragma unroll
  for(int mt=0;mt<4;mt++)
    #pragma unroll
    for(int p=0;p<4;p++) c2[mt][p] = (f32x4)(0.f);
  #pragma unroll
  for(int ks=0;ks<4;ks++){
    f16x8 a[4];
    #pragma unroll
    for(int mt=0;mt<4;mt++)
      a[mt] = *(const f16x8*)(&A2[mt*16+n16][ks*32+quad*8]);
    #pragma unroll
    for(int mt=0;mt<4;mt++)
      #pragma unroll
      for(int p=0;p<4;p++)
        c2[mt][p] = MFMA16(a[mt], b2[p][ks], c2[mt][p]);
  }
  #pragma unroll
  for(int mt=0;mt<4;mt++){
    int4 ev = *(const int4*)&vid_s[mt*16 + quad*4];
    int evv[4] = {ev.x, ev.y, ev.z, ev.w};
    #pragma unroll
    for(int p=0;p<2;p++){
      int colf = (2*w+p)*16 + n16;
      #pragma unroll
      for(int r=0;r<4;r++){
        float f  = sigmoidf_(c2[mt][p][r]   + shf[p]);
        float cc = softplusf_(c2[mt][p+2][r] + shc[p]);
        unsafeAtomicAdd(h_chem + (size_t)evv[r]*H_DIM + colf, f*cc);
      }
    }
  }
}

// fallback feat: h_chem fp32 + h_geom f16 separate
__global__ __launch_bounds__(256) void feat_split(
    const float* __restrict__ h_chem, const f16* __restrict__ h_geom,
    const f16* __restrict__ wf1f, const float* __restrict__ shf1,
    const f16* __restrict__ wf2f, const float* __restrict__ shf2,
    float* __restrict__ out)
{
  __shared__ __align__(16) f16 Af[64][200];
  const int t = threadIdx.x, w = t>>6, lane = t&63, n16 = lane&15, quad = lane>>4;
  const int v0 = blockIdx.x*64;

  for(int i=t;i<64*128;i+=256){ int r=i>>7, k=i&127; Af[r][k] = (f16)h_chem[(size_t)(v0+r)*128 + k]; }
  for(int i=t;i<64*64;i+=256){ int r=i>>6, k=i&63; Af[r][128+k] = h_geom[(size_t)(v0+r)*64 + k]; }

  f16x8 B1[2][6];
  #pragma unroll
  for(int p=0;p<2;p++){
    int col = (2*w+p)*16 + n16;
    #pragma unroll
    for(int ks=0;ks<6;ks++)
      B1[p][ks] = *(const f16x8*)(wf1f + (size_t)col*192 + ks*32 + quad*8);
  }
  __syncthreads();

  f32x4 c1[4][2];
  #pragma unroll
  for(int mt=0;mt<4;mt++){ c1[mt][0]=(f32x4)(0.f); c1[mt][1]=(f32x4)(0.f); }
  #pragma unroll
  for(int ks=0;ks<6;ks++){
    f16x8 a[4];
    #pragma unroll
    for(int mt=0;mt<4;mt++)
      a[mt] = *(const f16x8*)(&Af[mt*16+n16][ks*32+quad*8]);
    #pragma unroll
    for(int mt=0;mt<4;mt++)
      #pragma unroll
      for(int p=0;p<2;p++) c1[mt][p] = MFMA16(a[mt], B1[p][ks], c1[mt][p]);
  }
  __syncthreads();

  float s1v[2] = { shf1[(2*w+0)*16+n16], shf1[(2*w+1)*16+n16] };
  #pragma unroll
  for(int mt=0;mt<4;mt++)
    #pragma unroll
    for(int p=0;p<2;p++){
      int col = (2*w+p)*16 + n16;
      #pragma unroll
      for(int r=0;r<4;r++)
        Af[mt*16+quad*4+r][col] = (f16)siluf_(c1[mt][p][r] + s1v[p]);
    }
  __syncthreads();

  f16x8 B2[2][4];
  #pragma unroll
  for(int p=0;p<2;p++){
    int col = (2*w+p)*16 + n16;
    #pragma unroll
    for(int ks=0;ks<4;ks++)
      B2[p][ks] = *(const f16x8*)(wf2f + (size_t)col*128 + ks*32 + quad*8);
  }
  f32x4 c2[4][2];
  #pragma unroll
  for(int mt=0;mt<4;mt++){ c2[mt][0]=(f32x4)(0.f); c2[mt][1]=(f32x4)(0.f); }
  #pragma unroll
  for(int ks=0;ks<4;ks++){
    f16x8 a[4];
    #pragma unroll
    for(int mt=0;mt<4;mt++)
      a[mt] = *(const f16x8*)(&Af[mt*16+n16][ks*32+quad*8]);
    #pragma unroll
    for(int mt=0;mt<4;mt++)
      #pragma unroll
      for(int p=0;p<2;p++) c2[mt][p] = MFMA16(a[mt], B2[p][ks], c2[mt][p]);
  }
  float s2v[2] = { shf2[(2*w+0)*16+n16], shf2[(2*w+1)*16+n16] };
  #pragma unroll
  for(int mt=0;mt<4;mt++)
    #pragma unroll
    for(int p=0;p<2;p++){
      int col = (2*w+p)*16 + n16;
      #pragma unroll
      for(int r=0;r<4;r++)
        out[(size_t)(v0 + mt*16+quad*4+r)*128 + col] = c2[mt][p][r] + s2v[p];
    }
}

extern "C" void kernel_launch(void* const* d_in, const int* in_sizes, int n_in,
                              void* d_out, int out_size, void* d_ws, size_t ws_size,
                              hipStream_t stream) {
  const float* chem = (const float*)d_in[0];
  const float* geom = (const float*)d_in[1];
  const int*   vids = (const int*)d_in[2];
  const float* w1  = (const float*)d_in[3];
  const float* b1  = (const float*)d_in[4];
  const float* bn1 = (const float*)d_in[5];
  const float* w2  = (const float*)d_in[6];
  const float* b2  = (const float*)d_in[7];
  const float* bn2 = (const float*)d_in[8];
  const float* wg1 = (const float*)d_in[9];
  const float* bg1 = (const float*)d_in[10];
  const float* bng1= (const float*)d_in[11];
  const float* wg2 = (const float*)d_in[12];
  const float* bg2 = (const float*)d_in[13];
  const float* bng2= (const float*)d_in[14];
  const float* wf1 = (const float*)d_in[15];
  const float* bf1 = (const float*)d_in[16];
  const float* bnf1= (const float*)d_in[17];
  const float* wf2 = (const float*)d_in[18];
  const float* bf2 = (const float*)d_in[19];
  const float* bnf2= (const float*)d_in[20];
  float* out = (float*)d_out;
  char* ws = (char*)d_ws;

  const size_t NEED_BIG = 298765568ULL;   // gated 256M + h_feat 24M + sort 5M + weights
  const bool big = (ws_size >= NEED_BIG);

  if (big) {
    f16*   gated      = (f16*)  (ws + 0);              // 268435456
    f16*   h_feat     = (f16*)  (ws + 268435456);      // 25165824
    int*   perm       = (int*)  (ws + 293601280);      // 4194304
    int*   counts     = (int*)  (ws + 297795584);      // 262144
    int*   offsets    = (int*)  (ws + 298057728);      // 262400
    int*   offsets_wk = (int*)  (ws + 298320128);      // 262144
    char*  wb         = ws + 298582272;
    f16*   w1f  = (f16*)(wb);            // 16384
    f16*   w2f  = (f16*)(wb + 16384);    // 65536
    f16*   wg1f = (f16*)(wb + 81920);    // 8192
    f16*   wg2f = (f16*)(wb + 90112);    // 8192
    f16*   wf1f = (f16*)(wb + 98304);    // 49152
    f16*   wf2f = (f16*)(wb + 147456);   // 32768
    float* shift1  = (float*)(wb + 180224);
    float* shift2  = (float*)(wb + 180736);
    float* shiftg1 = (float*)(wb + 181760);
    float* shiftg2 = (float*)(wb + 182016);
    float* shiftf1 = (float*)(wb + 182272);
    float* shiftf2 = (float*)(wb + 182784);

    hipMemsetAsync(counts, 0, 65536*sizeof(int), stream);
    prep_kernel<<<dim3(128), dim3(256), 0, stream>>>(
        w1,b1,bn1, w2,b2,bn2, wg1,bg1,bng1, wg2,bg2,bng2, wf1,bf1,bnf1, wf2,bf2,bnf2,
        w1f,shift1, w2f,shift2, wg1f,shiftg1, wg2f,shiftg2, wf1f,shiftf1, wf2f,shiftf2);
    hist_kernel<<<dim3(1024), dim3(256), 0, stream>>>(vids, counts);
    scan_kernel<<<dim3(1), dim3(1024), 0, stream>>>(counts, offsets, offsets_wk);
    scatter_kernel<<<dim3(1024), dim3(256), 0, stream>>>(vids, offsets_wk, perm);
    chem_dense<<<dim3(E_CNT/64), dim3(256), 0, stream>>>(chem, w1f,shift1, w2f,shift2, gated);
    geom_mfma<<<dim3(V_CNT/64), dim3(256), 0, stream>>>(geom, wg1f,shiftg1, wg2f,shiftg2, h_feat, 192, 128);
    chem_agg<<<dim3(V_CNT/8), dim3(256), 0, stream>>>(gated, perm, offsets, h_feat);
    feat_mfma<<<dim3(V_CNT/64), dim3(256), 0, stream>>>(h_feat, wf1f,shiftf1, wf2f,shiftf2, out);
  } else {
    float* h_chem = (float*)(ws + 0);            // 33554432
    f16*   h_geom = (f16*)  (ws + 33554432);     // 8388608
    char*  wb     = ws + 41943040;
    f16*   w1f  = (f16*)(wb);
    f16*   w2f  = (f16*)(wb + 16384);
    f16*   wg1f = (f16*)(wb + 81920);
    f16*   wg2f = (f16*)(wb + 90112);
    f16*   wf1f = (f16*)(wb + 98304);
    f16*   wf2f = (f16*)(wb + 147456);
    float* shift1  = (float*)(wb + 180224);
    float* shift2  = (float*)(wb + 180736);
    float* shiftg1 = (float*)(wb + 181760);
    float* shiftg2 = (float*)(wb + 182016);
    float* shiftf1 = (float*)(wb + 182272);
    float* shiftf2 = (float*)(wb + 182784);

    prep_kernel<<<dim3(128), dim3(256), 0, stream>>>(
        w1,b1,bn1, w2,b2,bn2, wg1,bg1,bng1, wg2,bg2,bng2, wf1,bf1,bnf1, wf2,bf2,bnf2,
        w1f,shift1, w2f,shift2, wg1f,shiftg1, wg2f,shiftg2, wf1f,shiftf1, wf2f,shiftf2);
    zero_f4<<<dim3(4096), dim3(256), 0, stream>>>((float4*)h_chem, V_CNT*H_DIM/4);
    geom_mfma<<<dim3(V_CNT/64), dim3(256), 0, stream>>>(geom, wg1f,shiftg1, wg2f,shiftg2, h_geom, 64, 0);
    chem_atomic<<<dim3(E_CNT/64), dim3(256), 0, stream>>>(chem, vids, w1f,shift1, w2f,shift2, h_chem);
    feat_split<<<dim3(V_CNT/64), dim3(256), 0, stream>>>(h_chem, h_geom, wf1f,shiftf1, wf2f,shiftf2, out);
  }
}